// Round 5
// baseline (1127.848 us; speedup 1.0000x reference)
//
#include <hip/hip_runtime.h>
#include <cstdint>
#include <cstddef>

typedef __attribute__((ext_vector_type(8))) short short8;
typedef __attribute__((ext_vector_type(4))) short short4v;
typedef __attribute__((ext_vector_type(8))) __bf16 bf16x8;
typedef __attribute__((ext_vector_type(4))) float f32x4;
typedef unsigned short u16;

static constexpr int Bb = 32, Nn = 4096, NSs = 16, Dd = 512, Hh = 8, DFF = 2048;
static constexpr float SCALE = 0.125f;   // (64)^-0.5
static constexpr float EPSR  = 1e-8f;
static constexpr float LN_EPS = 1e-5f;

__device__ __forceinline__ u16 f2b(float x) {
  union { float f; uint32_t u; } a; a.f = x;
  uint32_t r = a.u + 0x7fffu + ((a.u >> 16) & 1u);
  return (u16)(r >> 16);
}
__device__ __forceinline__ float b2f(u16 x) {
  union { uint32_t u; float f; } a; a.u = ((uint32_t)x) << 16; return a.f;
}

__device__ __forceinline__ f32x4 mfma16(short8 a, short8 b, f32x4 c) {
  return __builtin_amdgcn_mfma_f32_16x16x32_bf16(
      __builtin_bit_cast(bf16x8, a), __builtin_bit_cast(bf16x8, b), c, 0, 0, 0);
}

// async global->LDS, 16B per lane; LDS dest must be wave-uniform base (+lane*16 HW)
__device__ __forceinline__ void gload16(const u16* g, u16* l) {
  __builtin_amdgcn_global_load_lds(
      (const __attribute__((address_space(1))) void*)g,
      (__attribute__((address_space(3))) void*)l, 16, 0, 0);
}

// ---------------- LayerNorm rows: fp32 [R,512] -> bf16 [R,512] ----------------
__global__ __launch_bounds__(256) void ln_rows(const float* __restrict__ src,
    const float* __restrict__ g, const float* __restrict__ bt,
    u16* __restrict__ dst, int R) {
  int row = blockIdx.x * 4 + (threadIdx.x >> 6);
  if (row >= R) return;
  int lane = threadIdx.x & 63;
  const float* p = src + (size_t)row * Dd + lane * 8;
  float4 u0 = *(const float4*)p;
  float4 u1 = *(const float4*)(p + 4);
  float x[8] = {u0.x,u0.y,u0.z,u0.w,u1.x,u1.y,u1.z,u1.w};
  float s = 0.f, s2 = 0.f;
#pragma unroll
  for (int e = 0; e < 8; ++e) { s += x[e]; s2 += x[e]*x[e]; }
#pragma unroll
  for (int m = 1; m < 64; m <<= 1) { s += __shfl_xor(s, m); s2 += __shfl_xor(s2, m); }
  float mean = s * (1.f/512.f);
  float var  = s2 * (1.f/512.f) - mean*mean;
  float rstd = rsqrtf(var + LN_EPS);
  union { u16 o[8]; short8 v; } ou;
#pragma unroll
  for (int e = 0; e < 8; ++e)
    ou.o[e] = f2b((x[e]-mean)*rstd*g[lane*8+e] + bt[lane*8+e]);
  *(short8*)(dst + (size_t)row * Dd + lane * 8) = ou.v;
}

// ---------------- GEMM 64x64 (small M), 2-phase dbuf + LDS swizzle -----------
// EP: 0 = bf16 out; 1 = f32 out + residual; 2 = bf16 out + bias + relu;
//     3 = f32 out + bias + residual
template<int EP>
__global__ __launch_bounds__(256) void gemm64(const u16* __restrict__ A,
    const u16* __restrict__ Bw, void* __restrict__ Cp,
    const float* __restrict__ bias, const float* __restrict__ res,
    int N, int K) {
  __shared__ u16 lA[2][64*32];
  __shared__ u16 lB[2][64*32];
  const int tid = threadIdx.x, lane = tid & 63, wid = tid >> 6;
  const int wr = wid >> 1, wc = wid & 1;
  const int bm = blockIdx.y * 64, bn = blockIdx.x * 64;
  f32x4 acc[2][2] = {};
  const int srow = wid*16 + (lane >> 2);
  const int scol = ((lane & 3) ^ ((lane >> 3) & 3)) * 8;
  const u16* Ap = A + (size_t)(bm + srow) * K + scol;
  const u16* Bp = Bw + (size_t)(bn + srow) * K + scol;
  const int ldb = wid * 512;
  const int li = lane & 15, lk = lane >> 4;
  const int csw = (lk ^ ((li >> 1) & 3)) * 8;
  const int nsteps = K >> 5;
  gload16(Ap, &lA[0][ldb]);
  gload16(Bp, &lB[0][ldb]);
  int cur = 0;
  for (int t = 0; t < nsteps; ++t) {
    __syncthreads();
    const int nx = cur ^ 1;
    if (t + 1 < nsteps) {
      const int k0 = (t + 1) * 32;
      gload16(Ap + k0, &lA[nx][ldb]);
      gload16(Bp + k0, &lB[nx][ldb]);
    }
    short8 af[2], bf[2];
#pragma unroll
    for (int m = 0; m < 2; ++m)
      af[m] = *(const short8*)&lA[cur][(wr*32 + m*16 + li)*32 + csw];
#pragma unroll
    for (int nn2 = 0; nn2 < 2; ++nn2)
      bf[nn2] = *(const short8*)&lB[cur][(wc*32 + nn2*16 + li)*32 + csw];
#pragma unroll
    for (int m = 0; m < 2; ++m)
#pragma unroll
      for (int nn2 = 0; nn2 < 2; ++nn2)
        acc[m][nn2] = mfma16(af[m], bf[nn2], acc[m][nn2]);
    cur = nx;
  }
  const int lr = lk * 4;
#pragma unroll
  for (int m = 0; m < 2; ++m)
#pragma unroll
    for (int nn2 = 0; nn2 < 2; ++nn2) {
      int row = bm + wr*32 + m*16 + lr;
      int col = bn + wc*32 + nn2*16 + li;
      f32x4 v = acc[m][nn2];
#pragma unroll
      for (int r = 0; r < 4; ++r) {
        size_t off = (size_t)(row + r) * N + col;
        float x = v[r];
        if constexpr (EP == 0) ((u16*)Cp)[off] = f2b(x);
        else if constexpr (EP == 1) ((float*)Cp)[off] = x + res[off];
        else if constexpr (EP == 2) { x += bias[col]; ((u16*)Cp)[off] = f2b(x > 0.f ? x : 0.f); }
        else ((float*)Cp)[off] = x + bias[col] + res[off];
      }
    }
}

// ---------------- q' kernel: q'[bi*8+h, e] = sum_d q[bi, h*64+d] * Wk[h*64+d, e]
// wkT[e][o] = Wk[o][e] (bf16). One output per thread, f32 accumulate.
__global__ __launch_bounds__(256) void qp_k(const u16* __restrict__ qb,
    const u16* __restrict__ wkT, u16* __restrict__ qpb) {
  int idx = blockIdx.x * 256 + threadIdx.x;     // 32*128*512
  int e = idx & 511, row = idx >> 9;            // row = bi*8 + h
  int h = row & 7, bi = row >> 3;
  const u16* qr = qb + (size_t)bi * 512 + h * 64;
  const u16* wr = wkT + (size_t)e * 512 + h * 64;
  float a = 0.f;
#pragma unroll
  for (int d = 0; d < 64; d += 8) {
    short8 qv = *(const short8*)(qr + d);
    short8 wv = *(const short8*)(wr + d);
#pragma unroll
    for (int t = 0; t < 8; ++t) a += b2f((u16)qv[t]) * b2f((u16)wv[t]);
  }
  qpb[idx] = f2b(a);
}

// ---------------- attention pass A2: dots = q' @ xn^T, column softmax --------
// per block: b, 64-j tile. LDS holds xn tile [64][512] (slot-swizzled), then
// is reused as the f32 score array sc[64][129] for the softmax phase.
__global__ __launch_bounds__(256) void attn_a2(const u16* __restrict__ qp,
    const u16* __restrict__ xn, u16* __restrict__ attnb,
    float* __restrict__ rowsum, float* __restrict__ attn_mean) {
  const int jt = blockIdx.x, b = blockIdx.y;
  const int tid = threadIdx.x, lane = tid & 63, wid = tid >> 6;
  __shared__ u16 lxn[64 * 512];        // 64 KB
  __shared__ float red[4][64];
  float (*sc)[129] = (float(*)[129])lxn;   // overlay (33 KB) after dots
  // stage xn tile [64 j][512 e]; store slot' = slot ^ (j&7) via pre-swizzled src
  {
    const u16* base = xn + ((size_t)b * Nn + jt * 64) * Dd;
#pragma unroll
    for (int r2 = 0; r2 < 16; ++r2) {
      int j = r2 * 4 + wid;
      gload16(base + (size_t)j * Dd + ((lane ^ (j & 7)) * 8), &lxn[j * 512]);
    }
  }
  __syncthreads();
  const int li = lane & 15, lk = lane >> 4;
  f32x4 acc[2][4] = {};
  const u16* qbase = qp + ((size_t)b * 128 + wid * 32) * Dd;
  for (int k = 0; k < 16; ++k) {
    short8 af[2], bf[4];
#pragma unroll
    for (int m = 0; m < 2; ++m)
      af[m] = *(const short8*)(qbase + (size_t)(m * 16 + li) * Dd + k * 32 + lk * 8);
#pragma unroll
    for (int n = 0; n < 4; ++n) {
      int j = n * 16 + li;
      bf[n] = *(const short8*)&lxn[j * 512 + (((k * 4 + lk) ^ (li & 7)) * 8)];
    }
#pragma unroll
    for (int m = 0; m < 2; ++m)
#pragma unroll
      for (int n = 0; n < 4; ++n)
        acc[m][n] = mfma16(af[m], bf[n], acc[m][n]);
  }
  __syncthreads();   // all waves done with lxn; reuse as sc
#pragma unroll
  for (int m = 0; m < 2; ++m)
#pragma unroll
    for (int n = 0; n < 4; ++n)
#pragma unroll
      for (int r = 0; r < 4; ++r)
        sc[n * 16 + li][wid * 32 + m * 16 + lk * 4 + r] = acc[m][n][r] * SCALE;
  __syncthreads();
  const int jl = tid & 63, qt = tid >> 6;
  float mx = -1e30f;
#pragma unroll
  for (int e = 0; e < 32; ++e) mx = fmaxf(mx, sc[jl][qt * 32 + e]);
  red[qt][jl] = mx;
  __syncthreads();
  float M = fmaxf(fmaxf(red[0][jl], red[1][jl]), fmaxf(red[2][jl], red[3][jl]));
  __syncthreads();
  float s = 0.f;
#pragma unroll
  for (int e = 0; e < 32; ++e) {
    float ev = __expf(sc[jl][qt * 32 + e] - M);
    sc[jl][qt * 32 + e] = ev; s += ev;
  }
  red[qt][jl] = s;
  __syncthreads();
  float S = red[0][jl] + red[1][jl] + red[2][jl] + red[3][jl];
  float inv = 1.f / S;
#pragma unroll
  for (int e = 0; e < 32; ++e)
    sc[jl][qt * 32 + e] = sc[jl][qt * 32 + e] * inv + EPSR;   // attn_before + EPS
  __syncthreads();
  if (tid < 128) {
    float rs = 0.f;
    for (int j2 = 0; j2 < 64; ++j2) rs += sc[j2][tid];
    atomicAdd(&rowsum[b * 128 + tid], rs);
  }
#pragma unroll
  for (int e = 0; e < 32; ++e) {
    int r = qt * 32 + e;
    attnb[((size_t)b * 128 + r) * Nn + jt * 64 + jl] = f2b(sc[jl][r]);
  }
  if (attn_mean != nullptr && tid < 64) {
    for (int i = 0; i < 16; ++i) {
      float sm = 0.f;
#pragma unroll
      for (int h = 0; h < 8; ++h) sm += sc[tid][i * 8 + h];
      attn_mean[((size_t)b * 16 + i) * Nn + jt * 64 + tid] = sm * 0.125f - EPSR;
    }
  }
}

// ---------------- attention pass B2: T[b,ih,e] = attnb[b] @ xn[b] ------------
// xnT layout [512 e][B*N]. Split K (j) in two halves -> Tpart[2][B][128][512].
__global__ __launch_bounds__(256) void attn_b2(const u16* __restrict__ attnb,
    const u16* __restrict__ xnT, float* __restrict__ Tpart) {
  const int et = blockIdx.x, jh = blockIdx.y, b = blockIdx.z;
  const int lane = threadIdx.x & 63, wid = threadIdx.x >> 6;
  const int li = lane & 15, lk = lane >> 4;
  const size_t BN = (size_t)Bb * Nn;
  const int j0 = jh * 2048;
  const u16* Ap = attnb + ((size_t)b * 128 + wid * 32 + li) * Nn + j0 + lk * 8;
  const u16* Bp = xnT + (size_t)(et * 64 + li) * BN + (size_t)b * Nn + j0 + lk * 8;
  f32x4 acc[2][4] = {};
  for (int k0 = 0; k0 < 2048; k0 += 32) {
    short8 af[2], bf[4];
#pragma unroll
    for (int m = 0; m < 2; ++m) af[m] = *(const short8*)(Ap + (size_t)m * 16 * Nn + k0);
#pragma unroll
    for (int n = 0; n < 4; ++n) bf[n] = *(const short8*)(Bp + (size_t)n * 16 * BN + k0);
#pragma unroll
    for (int m = 0; m < 2; ++m)
#pragma unroll
      for (int n = 0; n < 4; ++n)
        acc[m][n] = mfma16(af[m], bf[n], acc[m][n]);
  }
  float* Tout = Tpart + ((size_t)jh * Bb + b) * 128 * 512;
#pragma unroll
  for (int m = 0; m < 2; ++m)
#pragma unroll
    for (int n = 0; n < 4; ++n)
#pragma unroll
      for (int r = 0; r < 4; ++r)
        Tout[(size_t)(wid * 32 + m * 16 + lk * 4 + r) * 512 + et * 64 + n * 16 + li]
            = acc[m][n][r];
}

// ---------------- updates: updb[(b,i), o] = (T0+T1)[b][i*8+h(o)] . Wv[o,:] / rs
// wvT[e][o] = Wv[o][e] bf16; T in f32 (full precision path).
__global__ __launch_bounds__(256) void upd_k(const float* __restrict__ Tpart,
    const u16* __restrict__ wvT, const float* __restrict__ rs,
    u16* __restrict__ updb) {
  const int bi = blockIdx.x;          // b*16 + i
  const int b = bi >> 4, i = bi & 15;
  const int tid = threadIdx.x;
  __shared__ float lT[8][512];
  const float* T0 = Tpart + ((size_t)b * 128 + i * 8) * 512;
  const float* T1 = T0 + (size_t)Bb * 128 * 512;
  for (int t = tid; t < 4096; t += 256)
    lT[t >> 9][t & 511] = T0[t] + T1[t];
  __syncthreads();
#pragma unroll
  for (int half = 0; half < 2; ++half) {
    int o = half * 256 + tid;
    int h = o >> 6;
    float a = 0.f;
    for (int e = 0; e < 512; ++e)
      a += lT[h][e] * b2f(wvT[(size_t)e * 512 + o]);
    float r = rs[b * 128 + i * 8 + h];
    updb[(size_t)bi * 512 + o] = f2b(a / r);
  }
}

// ---------------- small utility kernels --------------------------------------
__global__ void cvt_w(const float* __restrict__ s, u16* __restrict__ d, int n) {
  int i = blockIdx.x*256 + threadIdx.x;
  if (i < n) d[i] = f2b(s[i]);
}
// tiled transpose+convert: d[C][R] = bf16(s[R][C]^T), s is f32
__global__ __launch_bounds__(256) void tr_cvt(const float* __restrict__ s,
    u16* __restrict__ d, int R, int C) {
  __shared__ u16 t[32][33];
  const int c0 = blockIdx.x*32, r0 = blockIdx.y*32;
  const int tr = threadIdx.x >> 3, tc4 = (threadIdx.x & 7)*4;
  float4 v = *(const float4*)&s[(size_t)(r0+tr)*C + c0 + tc4];
  t[tr][tc4+0] = f2b(v.x); t[tr][tc4+1] = f2b(v.y);
  t[tr][tc4+2] = f2b(v.z); t[tr][tc4+3] = f2b(v.w);
  __syncthreads();
  const int oc = threadIdx.x >> 3, or4 = (threadIdx.x & 7)*4;
  union { u16 o[4]; short4v v4; } ou;
#pragma unroll
  for (int e = 0; e < 4; ++e) ou.o[e] = t[or4+e][oc];
  *(short4v*)&d[(size_t)(c0+oc)*R + r0 + or4] = ou.v4;
}
// bf16 transpose: d[C][R] = s[R][C]^T  (both bf16)
__global__ __launch_bounds__(256) void tr16(const u16* __restrict__ s,
    u16* __restrict__ d, int R, int C) {
  __shared__ u16 t[32][33];
  const int c0 = blockIdx.x*32, r0 = blockIdx.y*32;
  const int tr = threadIdx.x >> 3, tc4 = (threadIdx.x & 7)*4;
  short4v v = *(const short4v*)&s[(size_t)(r0+tr)*C + c0 + tc4];
  t[tr][tc4+0] = (u16)v[0]; t[tr][tc4+1] = (u16)v[1];
  t[tr][tc4+2] = (u16)v[2]; t[tr][tc4+3] = (u16)v[3];
  __syncthreads();
  const int oc = threadIdx.x >> 3, or4 = (threadIdx.x & 7)*4;
  union { u16 o[4]; short4v v4; } ou;
#pragma unroll
  for (int e = 0; e < 4; ++e) ou.o[e] = t[or4+e][oc];
  *(short4v*)&d[(size_t)(c0+oc)*R + r0 + or4] = ou.v4;
}
__global__ void copy_f32v4(const float* __restrict__ s, float* __restrict__ d, int n4) {
  int i = blockIdx.x*256 + threadIdx.x;
  if (i < n4) ((float4*)d)[i] = ((const float4*)s)[i];
}

extern "C" void kernel_launch(void* const* d_in, const int* in_sizes, int n_in,
                              void* d_out, int out_size, void* d_ws, size_t ws_size,
                              hipStream_t stream) {
  (void)in_sizes; (void)n_in; (void)out_size; (void)ws_size;
  const float* inputs  = (const float*)d_in[0];
  const float* cond    = (const float*)d_in[1];
  const float* ln_in_g = (const float*)d_in[2];
  const float* ln_in_b = (const float*)d_in[3];
  const float* Wk = (const float*)d_in[4];
  const float* Wv = (const float*)d_in[5];
  const float* Wq = (const float*)d_in[6];
  const float* Wo = (const float*)d_in[7];
  const float* ln_s_g = (const float*)d_in[8];
  const float* ln_s_b = (const float*)d_in[9];
  const float* ln_f_g = (const float*)d_in[10];
  const float* ln_f_b = (const float*)d_in[11];
  const float* W1 = (const float*)d_in[12];
  const float* b1 = (const float*)d_in[13];
  const float* W2 = (const float*)d_in[14];
  const float* b2 = (const float*)d_in[15];
  float* out_slots = (float*)d_out;
  float* out_amean = (float*)d_out + (size_t)Bb*NSs*Dd;

  char* w = (char*)d_ws;
  auto alloc = [&](size_t bytes) {
    char* p = w; w += (bytes + 255) & ~(size_t)255; return p;
  };
  u16*  xn    = (u16*)alloc((size_t)Bb*Nn*Dd*2);        // [B*N][512]
  u16*  xnT   = (u16*)alloc((size_t)Bb*Nn*Dd*2);        // [512][B*N]
  u16*  attnb = (u16*)alloc((size_t)Bb*128*Nn*2);
  float* Tpart = (float*)alloc((size_t)2*Bb*128*512*4); // [2][B][128][512]
  float* slots = (float*)alloc((size_t)Bb*NSs*Dd*4);
  u16*  qb    = (u16*)alloc((size_t)Bb*NSs*Dd*2);
  u16*  qpb   = (u16*)alloc((size_t)Bb*128*Dd*2);       // q' [B*128][512]
  u16*  snb   = (u16*)alloc((size_t)Bb*NSs*Dd*2);
  u16*  s2nb  = (u16*)alloc((size_t)Bb*NSs*Dd*2);
  u16*  h1b   = (u16*)alloc((size_t)Bb*NSs*DFF*2);
  u16*  updb  = (u16*)alloc((size_t)Bb*NSs*Dd*2);
  float* rowsum = (float*)alloc((size_t)Bb*128*3*4);    // one per iteration
  u16*  wqb = (u16*)alloc(262144*2);
  u16*  wob = (u16*)alloc(262144*2);
  u16*  wkT = (u16*)alloc(262144*2);                    // Wk^T bf16 [e][o]
  u16*  wvT = (u16*)alloc(262144*2);                    // Wv^T bf16 [e][o]
  u16*  w1t = (u16*)alloc((size_t)1048576*2);
  u16*  w2t = (u16*)alloc((size_t)1048576*2);

  // weights
  cvt_w<<<1024, 256, 0, stream>>>(Wq, wqb, 262144);
  cvt_w<<<1024, 256, 0, stream>>>(Wo, wob, 262144);
  tr_cvt<<<dim3(16, 16), 256, 0, stream>>>(Wk, wkT, 512, 512);
  tr_cvt<<<dim3(16, 16), 256, 0, stream>>>(Wv, wvT, 512, 512);
  tr_cvt<<<dim3(64, 16), 256, 0, stream>>>(W1, w1t, 512, 2048);
  tr_cvt<<<dim3(16, 64), 256, 0, stream>>>(W2, w2t, 2048, 512);
  copy_f32v4<<<256, 256, 0, stream>>>(cond, slots, 65536);
  hipMemsetAsync(rowsum, 0, (size_t)Bb*128*3*4, stream);
  // x = LN(inputs) -> bf16, then transpose
  ln_rows<<<Bb*Nn/4, 256, 0, stream>>>(inputs, ln_in_g, ln_in_b, xn, Bb*Nn);
  tr16<<<dim3(16, Bb*Nn/32), 256, 0, stream>>>(xn, xnT, Bb*Nn, 512);

  for (int it = 0; it < 3; ++it) {
    float* rsp = rowsum + (size_t)it * Bb * 128;
    ln_rows<<<128, 256, 0, stream>>>(slots, ln_s_g, ln_s_b, snb, Bb*NSs);
    gemm64<0><<<dim3(8, 8), 256, 0, stream>>>(snb, wqb, qb, nullptr, nullptr, 512, 512);
    qp_k<<<8192, 256, 0, stream>>>(qb, wkT, qpb);
    attn_a2<<<dim3(Nn/64, Bb), 256, 0, stream>>>(qpb, xn, attnb, rsp,
                                                 it == 2 ? out_amean : nullptr);
    attn_b2<<<dim3(8, 2, Bb), 256, 0, stream>>>(attnb, xnT, Tpart);
    upd_k<<<Bb*NSs, 256, 0, stream>>>(Tpart, wvT, rsp, updb);
    gemm64<1><<<dim3(8, 8), 256, 0, stream>>>(updb, wob, slots, nullptr, slots, 512, 512);
    ln_rows<<<128, 256, 0, stream>>>(slots, ln_f_g, ln_f_b, s2nb, Bb*NSs);
    gemm64<2><<<dim3(32, 8), 256, 0, stream>>>(s2nb, w1t, h1b, b1, nullptr, 2048, 512);
    gemm64<3><<<dim3(8, 8), 256, 0, stream>>>(h1b, w2t, slots, b2, slots, 512, 2048);
  }
  copy_f32v4<<<256, 256, 0, stream>>>(slots, out_slots, 65536);
}

// Round 6
// 706.336 us; speedup vs baseline: 1.5968x; 1.5968x over previous
//
#include <hip/hip_runtime.h>
#include <cstdint>
#include <cstddef>

typedef __attribute__((ext_vector_type(8))) short short8;
typedef __attribute__((ext_vector_type(4))) short short4v;
typedef __attribute__((ext_vector_type(8))) __bf16 bf16x8;
typedef __attribute__((ext_vector_type(4))) float f32x4;
typedef unsigned short u16;

static constexpr int Bb = 32, Nn = 4096, NSs = 16, Dd = 512, Hh = 8, DFF = 2048;
static constexpr float SCALE = 0.125f;   // (64)^-0.5
static constexpr float EPSR  = 1e-8f;
static constexpr float LN_EPS = 1e-5f;

__device__ __forceinline__ u16 f2b(float x) {
  union { float f; uint32_t u; } a; a.f = x;
  uint32_t r = a.u + 0x7fffu + ((a.u >> 16) & 1u);
  return (u16)(r >> 16);
}

__device__ __forceinline__ f32x4 mfma16(short8 a, short8 b, f32x4 c) {
  return __builtin_amdgcn_mfma_f32_16x16x32_bf16(
      __builtin_bit_cast(bf16x8, a), __builtin_bit_cast(bf16x8, b), c, 0, 0, 0);
}

// async global->LDS, 16B per lane; LDS dest must be wave-uniform base (+lane*16 HW)
__device__ __forceinline__ void gload16(const u16* g, u16* l) {
  __builtin_amdgcn_global_load_lds(
      (const __attribute__((address_space(1))) void*)g,
      (__attribute__((address_space(3))) void*)l, 16, 0, 0);
}

// ---------------- LayerNorm rows: fp32 [R,512] -> bf16 [R,512] ----------------
__global__ __launch_bounds__(256) void ln_rows(const float* __restrict__ src,
    const float* __restrict__ g, const float* __restrict__ bt,
    u16* __restrict__ dst, int R) {
  int row = blockIdx.x * 4 + (threadIdx.x >> 6);
  if (row >= R) return;
  int lane = threadIdx.x & 63;
  const float* p = src + (size_t)row * Dd + lane * 8;
  float4 u0 = *(const float4*)p;
  float4 u1 = *(const float4*)(p + 4);
  float x[8] = {u0.x,u0.y,u0.z,u0.w,u1.x,u1.y,u1.z,u1.w};
  float s = 0.f, s2 = 0.f;
#pragma unroll
  for (int e = 0; e < 8; ++e) { s += x[e]; s2 += x[e]*x[e]; }
#pragma unroll
  for (int m = 1; m < 64; m <<= 1) { s += __shfl_xor(s, m); s2 += __shfl_xor(s2, m); }
  float mean = s * (1.f/512.f);
  float var  = s2 * (1.f/512.f) - mean*mean;
  float rstd = rsqrtf(var + LN_EPS);
  union { u16 o[8]; short8 v; } ou;
#pragma unroll
  for (int e = 0; e < 8; ++e)
    ou.o[e] = f2b((x[e]-mean)*rstd*g[lane*8+e] + bt[lane*8+e]);
  *(short8*)(dst + (size_t)row * Dd + lane * 8) = ou.v;
}

// ---------------- fused K/V GEMM 128x128, BK=64 single-buffer ----------------
// 64 MFMA/wave per barrier pair (2x the BK=32 version), 8 K-steps, 48KB LDS
// -> 3 blocks/CU. Row stride 128B = 32 banks exactly, so conflict-free needs
// slot' = slot ^ (row&7): 8 lanes per 4-bank group = b128 minimum (balanced).
// Stage side (gload_lds writes linearly): pre-swizzle the GLOBAL source col.
__global__ __launch_bounds__(256, 2) void gemm_kv(const u16* __restrict__ A,
    const u16* __restrict__ Bk, const u16* __restrict__ Bv,
    u16* __restrict__ Ck, u16* __restrict__ CvT) {
  __shared__ u16 lA[128*64];
  __shared__ u16 lK[128*64];
  __shared__ u16 lV[128*64];
  const int tid = threadIdx.x, lane = tid & 63, wid = tid >> 6;
  const int wr = wid >> 1, wc = wid & 1;
  // bijective XCD swizzle: nwg=4096, 8 XCDs, 512 per XCD
  const int n  = blockIdx.y * 4 + blockIdx.x;
  const int orig = (n & 7) * 512 + (n >> 3);
  const int bm = (orig >> 2) * 128, bn = (orig & 3) * 128;
  const size_t BN = (size_t)Bb * Nn;
  f32x4 ak[4][4] = {};
  f32x4 av[4][4] = {};
  // staging: lane covers row (lane>>3), 16B slot (lane&7) of a 1KB 8-row chunk
  const int sr = lane >> 3;
  const int ss = ((lane & 7) ^ (sr & 7)) * 8;   // swizzled source col (u16)
  const int li = lane & 15, lk = lane >> 4;
  const int sx = (li & 7) * 8;                  // read-side XOR (u16 units)
  for (int t = 0; t < 8; ++t) {
    const int k0 = t * 64;
    __syncthreads();       // previous compute done -> safe to overwrite
#pragma unroll
    for (int gi = 0; gi < 4; ++gi) {
      const int rb = wid * 32 + gi * 8;
      gload16(A  + (size_t)(bm + rb + sr) * Dd + k0 + ss, &lA[rb * 64]);
      gload16(Bk + (size_t)(bn + rb + sr) * Dd + k0 + ss, &lK[rb * 64]);
      gload16(Bv + (size_t)(bn + rb + sr) * Dd + k0 + ss, &lV[rb * 64]);
    }
    __syncthreads();       // compiler drains vmcnt(0): tile ready
#pragma unroll
    for (int kk = 0; kk < 2; ++kk) {
      const int cs = ((kk * 4 + lk) * 8) ^ sx;  // swizzled col (u16)
      short8 af[4], kf[4], vf[4];
#pragma unroll
      for (int m = 0; m < 4; ++m)
        af[m] = *(const short8*)&lA[(wr*64 + m*16 + li)*64 + cs];
#pragma unroll
      for (int nn2 = 0; nn2 < 4; ++nn2) {
        kf[nn2] = *(const short8*)&lK[(wc*64 + nn2*16 + li)*64 + cs];
        vf[nn2] = *(const short8*)&lV[(wc*64 + nn2*16 + li)*64 + cs];
      }
#pragma unroll
      for (int m = 0; m < 4; ++m)
#pragma unroll
        for (int nn2 = 0; nn2 < 4; ++nn2) {
          ak[m][nn2] = mfma16(af[m], kf[nn2], ak[m][nn2]);
          av[m][nn2] = mfma16(af[m], vf[nn2], av[m][nn2]);
        }
    }
  }
  const int lr = lk * 4;
#pragma unroll
  for (int m = 0; m < 4; ++m)
#pragma unroll
    for (int nn2 = 0; nn2 < 4; ++nn2) {
      int row = bm + wr*64 + m*16 + lr;
      int col = bn + wc*64 + nn2*16 + li;
      f32x4 vk = ak[m][nn2];
#pragma unroll
      for (int r = 0; r < 4; ++r)
        Ck[(size_t)(row + r) * Dd + col] = f2b(vk[r]);
      f32x4 vv = av[m][nn2];
      union { u16 o[4]; short4v v4; } ou;
#pragma unroll
      for (int r = 0; r < 4; ++r) ou.o[r] = f2b(vv[r]);
      // vT[col][row..row+3] — 8B contiguous per lane
      *(short4v*)&CvT[(size_t)col * BN + row] = ou.v4;
    }
}

// ---------------- GEMM 64x64 (small M), 2-phase dbuf + LDS swizzle -----------
// EP: 0 = bf16 out; 1 = f32 out + residual; 2 = bf16 out + bias + relu;
//     3 = f32 out + bias + residual
template<int EP>
__global__ __launch_bounds__(256) void gemm64(const u16* __restrict__ A,
    const u16* __restrict__ Bw, void* __restrict__ Cp,
    const float* __restrict__ bias, const float* __restrict__ res,
    int N, int K) {
  __shared__ u16 lA[2][64*32];
  __shared__ u16 lB[2][64*32];
  const int tid = threadIdx.x, lane = tid & 63, wid = tid >> 6;
  const int wr = wid >> 1, wc = wid & 1;
  const int bm = blockIdx.y * 64, bn = blockIdx.x * 64;
  f32x4 acc[2][2] = {};
  const int srow = wid*16 + (lane >> 2);
  const int scol = ((lane & 3) ^ ((lane >> 3) & 3)) * 8;
  const u16* Ap = A + (size_t)(bm + srow) * K + scol;
  const u16* Bp = Bw + (size_t)(bn + srow) * K + scol;
  const int ldb = wid * 512;
  const int li = lane & 15, lk = lane >> 4;
  const int csw = (lk ^ ((li >> 1) & 3)) * 8;
  const int nsteps = K >> 5;
  gload16(Ap, &lA[0][ldb]);
  gload16(Bp, &lB[0][ldb]);
  int cur = 0;
  for (int t = 0; t < nsteps; ++t) {
    __syncthreads();
    const int nx = cur ^ 1;
    if (t + 1 < nsteps) {
      const int k0 = (t + 1) * 32;
      gload16(Ap + k0, &lA[nx][ldb]);
      gload16(Bp + k0, &lB[nx][ldb]);
    }
    short8 af[2], bf[2];
#pragma unroll
    for (int m = 0; m < 2; ++m)
      af[m] = *(const short8*)&lA[cur][(wr*32 + m*16 + li)*32 + csw];
#pragma unroll
    for (int nn2 = 0; nn2 < 2; ++nn2)
      bf[nn2] = *(const short8*)&lB[cur][(wc*32 + nn2*16 + li)*32 + csw];
#pragma unroll
    for (int m = 0; m < 2; ++m)
#pragma unroll
      for (int nn2 = 0; nn2 < 2; ++nn2)
        acc[m][nn2] = mfma16(af[m], bf[nn2], acc[m][nn2]);
    cur = nx;
  }
  const int lr = lk * 4;
#pragma unroll
  for (int m = 0; m < 2; ++m)
#pragma unroll
    for (int nn2 = 0; nn2 < 2; ++nn2) {
      int row = bm + wr*32 + m*16 + lr;
      int col = bn + wc*32 + nn2*16 + li;
      f32x4 v = acc[m][nn2];
#pragma unroll
      for (int r = 0; r < 4; ++r) {
        size_t off = (size_t)(row + r) * N + col;
        float x = v[r];
        if constexpr (EP == 0) ((u16*)Cp)[off] = f2b(x);
        else if constexpr (EP == 1) ((float*)Cp)[off] = x + res[off];
        else if constexpr (EP == 2) { x += bias[col]; ((u16*)Cp)[off] = f2b(x > 0.f ? x : 0.f); }
        else ((float*)Cp)[off] = x + bias[col] + res[off];
      }
    }
}

// ---------------- attention pass A: dots + column softmax + renorm prep ------
__global__ __launch_bounds__(256) void attn_a(const u16* __restrict__ q,
    const u16* __restrict__ kk, u16* __restrict__ attnb,
    float* __restrict__ rowsum, float* __restrict__ attn_mean) {
  const int jt = blockIdx.x, b = blockIdx.y;
  const int tid = threadIdx.x, lane = tid & 63, wid = tid >> 6;
  __shared__ float sc[64][129];   // [j_local][ih]
  __shared__ float red[4][64];
  const int li = lane & 15, lk = lane >> 4;
#pragma unroll
  for (int hh = 0; hh < 2; ++hh) {
    const int h = wid * 2 + hh;
    const u16* qb = q + (((size_t)b*16 + li)*8 + h)*64 + lk*8;
    short8 a0 = *(const short8*)qb;
    short8 a1 = *(const short8*)(qb + 32);
#pragma unroll
    for (int n = 0; n < 4; ++n) {
      const u16* kb = kk + ((size_t)b*Nn + jt*64 + n*16 + li)*Dd + h*64 + lk*8;
      f32x4 acc = {};
      acc = mfma16(a0, *(const short8*)kb, acc);
      acc = mfma16(a1, *(const short8*)(kb + 32), acc);
#pragma unroll
      for (int r = 0; r < 4; ++r)
        sc[n*16 + li][(lk*4 + r)*8 + h] = acc[r] * SCALE;
    }
  }
  __syncthreads();
  const int jl = tid & 63, qt = tid >> 6;
  float mx = -1e30f;
#pragma unroll
  for (int e = 0; e < 32; ++e) mx = fmaxf(mx, sc[jl][qt*32 + e]);
  red[qt][jl] = mx;
  __syncthreads();
  float M = fmaxf(fmaxf(red[0][jl], red[1][jl]), fmaxf(red[2][jl], red[3][jl]));
  __syncthreads();
  float s = 0.f;
#pragma unroll
  for (int e = 0; e < 32; ++e) {
    float ev = __expf(sc[jl][qt*32 + e] - M);
    sc[jl][qt*32 + e] = ev; s += ev;
  }
  red[qt][jl] = s;
  __syncthreads();
  float S = red[0][jl] + red[1][jl] + red[2][jl] + red[3][jl];
  float inv = 1.f / S;
#pragma unroll
  for (int e = 0; e < 32; ++e)
    sc[jl][qt*32 + e] = sc[jl][qt*32 + e] * inv + EPSR;   // attn_before + EPS
  __syncthreads();
  if (tid < 128) {
    float rs = 0.f;
    for (int j2 = 0; j2 < 64; ++j2) rs += sc[j2][tid];
    atomicAdd(&rowsum[b*128 + tid], rs);
  }
#pragma unroll
  for (int e = 0; e < 32; ++e) {
    int r = qt*32 + e;
    attnb[((size_t)b*128 + r)*Nn + jt*64 + jl] = f2b(sc[jl][r]);
  }
  if (attn_mean != nullptr && tid < 64) {
    for (int i = 0; i < 16; ++i) {
      float sm = 0.f;
#pragma unroll
      for (int h = 0; h < 8; ++h) sm += sc[tid][i*8 + h];
      attn_mean[((size_t)b*16 + i)*Nn + jt*64 + tid] = sm * 0.125f - EPSR;
    }
  }
}

// ---------------- attention pass B: partial updates = attn @ v ---------------
// vT layout: [d_out = h*64+d][b*N + j]. j split 4 ways for occupancy (was 256
// blocks = 1 block/CU pure latency chain; now 1024 blocks, same traffic).
// Tpart layout: [js][b][h][i(16)][d(64)] f32.
__global__ __launch_bounds__(256) void attn_b(const u16* __restrict__ attnb,
    const u16* __restrict__ vT, float* __restrict__ Tpart) {
  const int h = blockIdx.x, js = blockIdx.y, b = blockIdx.z;
  const int lane = threadIdx.x & 63, wid = threadIdx.x >> 6;
  const int li = lane & 15, lk = lane >> 4;
  const size_t BN = (size_t)Bb * Nn;
  const int j0 = js * 1024;
  const u16* Ap = attnb + ((size_t)b*128 + li*8 + h)*Nn + j0 + lk*8;
  const u16* Bp = vT + (size_t)(h*64 + wid*16 + li)*BN + (size_t)b*Nn + j0 + lk*8;
  f32x4 acc[4] = {};
  for (int k0 = 0; k0 < 1024; k0 += 128) {
#pragma unroll
    for (int e = 0; e < 4; ++e)
      acc[e] = mfma16(*(const short8*)(Ap + k0 + e*32),
                      *(const short8*)(Bp + k0 + e*32), acc[e]);
  }
  float* Tout = Tpart + ((((size_t)js * Bb + b) * 8 + h) * 16) * 64;
#pragma unroll
  for (int r = 0; r < 4; ++r) {
    int i = lk*4 + r;
    float t = acc[0][r] + acc[1][r] + acc[2][r] + acc[3][r];
    Tout[(size_t)i * 64 + wid*16 + li] = t;
  }
}

// combine partials + renormalize: updb[(b*16+i)*512 + h*64+d]
__global__ void upd_c(const float* __restrict__ Tpart,
    const float* __restrict__ rs, u16* __restrict__ updb) {
  int idx = blockIdx.x * 256 + threadIdx.x;   // 262144 total
  int o = idx & 511, bi = idx >> 9;
  int b = bi >> 4, i = bi & 15;
  int h = o >> 6, d = o & 63;
  size_t base = (((size_t)b * 8 + h) * 16 + i) * 64 + d;
  const size_t stride = (size_t)Bb * 8 * 16 * 64;
  float t = Tpart[base] + Tpart[base + stride]
          + Tpart[base + 2*stride] + Tpart[base + 3*stride];
  updb[idx] = f2b(t / rs[b * 128 + i * 8 + h]);
}

// ---------------- small utility kernels --------------------------------------
__global__ void cvt_w(const float* __restrict__ s, u16* __restrict__ d, int n) {
  int i = blockIdx.x*256 + threadIdx.x;
  if (i < n) d[i] = f2b(s[i]);
}
// tiled transpose+convert: d[C][R] = bf16(s[R][C]^T)
__global__ __launch_bounds__(256) void tr_cvt(const float* __restrict__ s,
    u16* __restrict__ d, int R, int C) {
  __shared__ u16 t[32][33];
  const int c0 = blockIdx.x*32, r0 = blockIdx.y*32;
  const int tr = threadIdx.x >> 3, tc4 = (threadIdx.x & 7)*4;
  float4 v = *(const float4*)&s[(size_t)(r0+tr)*C + c0 + tc4];
  t[tr][tc4+0] = f2b(v.x); t[tr][tc4+1] = f2b(v.y);
  t[tr][tc4+2] = f2b(v.z); t[tr][tc4+3] = f2b(v.w);
  __syncthreads();
  const int oc = threadIdx.x >> 3, or4 = (threadIdx.x & 7)*4;
  union { u16 o[4]; short4v v4; } ou;
#pragma unroll
  for (int e = 0; e < 4; ++e) ou.o[e] = t[or4+e][oc];
  *(short4v*)&d[(size_t)(c0+oc)*R + r0 + or4] = ou.v4;
}
__global__ void copy_f32v4(const float* __restrict__ s, float* __restrict__ d, int n4) {
  int i = blockIdx.x*256 + threadIdx.x;
  if (i < n4) ((float4*)d)[i] = ((const float4*)s)[i];
}

extern "C" void kernel_launch(void* const* d_in, const int* in_sizes, int n_in,
                              void* d_out, int out_size, void* d_ws, size_t ws_size,
                              hipStream_t stream) {
  (void)in_sizes; (void)n_in; (void)out_size; (void)ws_size;
  const float* inputs  = (const float*)d_in[0];
  const float* cond    = (const float*)d_in[1];
  const float* ln_in_g = (const float*)d_in[2];
  const float* ln_in_b = (const float*)d_in[3];
  const float* Wk = (const float*)d_in[4];
  const float* Wv = (const float*)d_in[5];
  const float* Wq = (const float*)d_in[6];
  const float* Wo = (const float*)d_in[7];
  const float* ln_s_g = (const float*)d_in[8];
  const float* ln_s_b = (const float*)d_in[9];
  const float* ln_f_g = (const float*)d_in[10];
  const float* ln_f_b = (const float*)d_in[11];
  const float* W1 = (const float*)d_in[12];
  const float* b1 = (const float*)d_in[13];
  const float* W2 = (const float*)d_in[14];
  const float* b2 = (const float*)d_in[15];
  float* out_slots = (float*)d_out;
  float* out_amean = (float*)d_out + (size_t)Bb*NSs*Dd;

  char* w = (char*)d_ws;
  auto alloc = [&](size_t bytes) {
    char* p = w; w += (bytes + 255) & ~(size_t)255; return p;
  };
  u16*  xn    = (u16*)alloc((size_t)Bb*Nn*Dd*2);
  u16*  kbuf  = (u16*)alloc((size_t)Bb*Nn*Dd*2);
  u16*  vT    = (u16*)alloc((size_t)Bb*Nn*Dd*2);   // [512][B*N]
  u16*  attnb = (u16*)alloc((size_t)Bb*128*Nn*2);
  float* Tpart = (float*)alloc((size_t)4*Bb*8*16*64*4);  // [js][b][h][i][d]
  float* slots = (float*)alloc((size_t)Bb*NSs*Dd*4);
  u16*  qb    = (u16*)alloc((size_t)Bb*NSs*Dd*2);
  u16*  snb   = (u16*)alloc((size_t)Bb*NSs*Dd*2);
  u16*  s2nb  = (u16*)alloc((size_t)Bb*NSs*Dd*2);
  u16*  h1b   = (u16*)alloc((size_t)Bb*NSs*DFF*2);
  u16*  updb  = (u16*)alloc((size_t)Bb*NSs*Dd*2);
  float* rowsum = (float*)alloc((size_t)Bb*128*3*4);   // one per iteration
  u16*  wkb = (u16*)alloc(262144*2);
  u16*  wvb = (u16*)alloc(262144*2);
  u16*  wqb = (u16*)alloc(262144*2);
  u16*  wob = (u16*)alloc(262144*2);
  u16*  w1t = (u16*)alloc((size_t)1048576*2);
  u16*  w2t = (u16*)alloc((size_t)1048576*2);

  // weights -> bf16 (W1/W2 transposed so B-operand is [out,K] row-major)
  cvt_w<<<1024, 256, 0, stream>>>(Wk, wkb, 262144);
  cvt_w<<<1024, 256, 0, stream>>>(Wv, wvb, 262144);
  cvt_w<<<1024, 256, 0, stream>>>(Wq, wqb, 262144);
  cvt_w<<<1024, 256, 0, stream>>>(Wo, wob, 262144);
  tr_cvt<<<dim3(64, 16), 256, 0, stream>>>(W1, w1t, 512, 2048);
  tr_cvt<<<dim3(16, 64), 256, 0, stream>>>(W2, w2t, 2048, 512);
  // slots <- conditioning; rowsum <- 0 (all 3 iterations)
  copy_f32v4<<<256, 256, 0, stream>>>(cond, slots, 65536);
  (void)hipMemsetAsync(rowsum, 0, (size_t)Bb*128*3*4, stream);
  // x = LN(inputs) -> bf16
  ln_rows<<<Bb*Nn/4, 256, 0, stream>>>(inputs, ln_in_g, ln_in_b, xn, Bb*Nn);
  // fused: k = x @ Wk^T  [B*N,512]  and  vT = (x @ Wv^T)^T  [512, B*N]
  gemm_kv<<<dim3(4, Bb*Nn/128), 256, 0, stream>>>(xn, wkb, wvb, kbuf, vT);

  for (int it = 0; it < 3; ++it) {
    float* rsp = rowsum + (size_t)it * Bb * 128;
    ln_rows<<<128, 256, 0, stream>>>(slots, ln_s_g, ln_s_b, snb, Bb*NSs);
    gemm64<0><<<dim3(8, 8), 256, 0, stream>>>(snb, wqb, qb, nullptr, nullptr, 512, 512);
    attn_a<<<dim3(Nn/64, Bb), 256, 0, stream>>>(qb, kbuf, attnb, rsp,
                                                it == 2 ? out_amean : nullptr);
    attn_b<<<dim3(Hh, 4, Bb), 256, 0, stream>>>(attnb, vT, Tpart);
    upd_c<<<1024, 256, 0, stream>>>(Tpart, rsp, updb);
    gemm64<1><<<dim3(8, 8), 256, 0, stream>>>(updb, wob, slots, nullptr, slots, 512, 512);
    ln_rows<<<128, 256, 0, stream>>>(slots, ln_f_g, ln_f_b, s2nb, Bb*NSs);
    gemm64<2><<<dim3(32, 8), 256, 0, stream>>>(s2nb, w1t, h1b, b1, nullptr, 2048, 512);
    gemm64<3><<<dim3(8, 8), 256, 0, stream>>>(h1b, w2t, slots, b2, slots, 512, 2048);
  }
  copy_f32v4<<<256, 256, 0, stream>>>(slots, out_slots, 65536);
}

// Round 7
// 705.937 us; speedup vs baseline: 1.5977x; 1.0006x over previous
//
#include <hip/hip_runtime.h>
#include <cstdint>
#include <cstddef>

typedef __attribute__((ext_vector_type(8))) short short8;
typedef __attribute__((ext_vector_type(4))) short short4v;
typedef __attribute__((ext_vector_type(8))) __bf16 bf16x8;
typedef __attribute__((ext_vector_type(4))) float f32x4;
typedef unsigned short u16;

static constexpr int Bb = 32, Nn = 4096, NSs = 16, Dd = 512, Hh = 8, DFF = 2048;
static constexpr float SCALE = 0.125f;   // (64)^-0.5
static constexpr float EPSR  = 1e-8f;
static constexpr float LN_EPS = 1e-5f;

__device__ __forceinline__ u16 f2b(float x) {
  union { float f; uint32_t u; } a; a.f = x;
  uint32_t r = a.u + 0x7fffu + ((a.u >> 16) & 1u);
  return (u16)(r >> 16);
}

__device__ __forceinline__ f32x4 mfma16(short8 a, short8 b, f32x4 c) {
  return __builtin_amdgcn_mfma_f32_16x16x32_bf16(
      __builtin_bit_cast(bf16x8, a), __builtin_bit_cast(bf16x8, b), c, 0, 0, 0);
}

// async global->LDS, 16B per lane; LDS dest must be wave-uniform base (+lane*16 HW)
__device__ __forceinline__ void gload16(const u16* g, u16* l) {
  __builtin_amdgcn_global_load_lds(
      (const __attribute__((address_space(1))) void*)g,
      (__attribute__((address_space(3))) void*)l, 16, 0, 0);
}

// ---------------- LayerNorm rows: fp32 [R,512] -> bf16 [R,512] ----------------
__global__ __launch_bounds__(256) void ln_rows(const float* __restrict__ src,
    const float* __restrict__ g, const float* __restrict__ bt,
    u16* __restrict__ dst, int R) {
  int row = blockIdx.x * 4 + (threadIdx.x >> 6);
  if (row >= R) return;
  int lane = threadIdx.x & 63;
  const float* p = src + (size_t)row * Dd + lane * 8;
  float4 u0 = *(const float4*)p;
  float4 u1 = *(const float4*)(p + 4);
  float x[8] = {u0.x,u0.y,u0.z,u0.w,u1.x,u1.y,u1.z,u1.w};
  float s = 0.f, s2 = 0.f;
#pragma unroll
  for (int e = 0; e < 8; ++e) { s += x[e]; s2 += x[e]*x[e]; }
#pragma unroll
  for (int m = 1; m < 64; m <<= 1) { s += __shfl_xor(s, m); s2 += __shfl_xor(s2, m); }
  float mean = s * (1.f/512.f);
  float var  = s2 * (1.f/512.f) - mean*mean;
  float rstd = rsqrtf(var + LN_EPS);
  union { u16 o[8]; short8 v; } ou;
#pragma unroll
  for (int e = 0; e < 8; ++e)
    ou.o[e] = f2b((x[e]-mean)*rstd*g[lane*8+e] + bt[lane*8+e]);
  *(short8*)(dst + (size_t)row * Dd + lane * 8) = ou.v;
}

// ---------------- fused K/V GEMM 128x128: dbuf + COUNTED vmcnt (T4) ----------
// Per iter: {issue 6 gloads -> buf nx; s_waitcnt vmcnt(6) [waits only the
// PREVIOUS stage]; s_barrier; compute(cur); s_barrier}. The counted wait lets
// the prefetch stay in flight across the whole compute phase -- __syncthreads
// would drain vmcnt(0) on the just-issued loads (the ~72% stall, m233/m218).
// LDS swizzle (verified conflict-free in R4): source col ^((lane>>3)&3),
// read col lk^((li>>1)&3).
__global__ __launch_bounds__(256, 2) void gemm_kv(const u16* __restrict__ A,
    const u16* __restrict__ Bk, const u16* __restrict__ Bv,
    u16* __restrict__ Ck, u16* __restrict__ CvT) {
  __shared__ u16 lA[2][128*32];
  __shared__ u16 lK[2][128*32];
  __shared__ u16 lV[2][128*32];
  const int tid = threadIdx.x, lane = tid & 63, wid = tid >> 6;
  const int wr = wid >> 1, wc = wid & 1;
  // bijective XCD swizzle: nwg=4096, 8 XCDs, 512 per XCD
  const int n  = blockIdx.y * 4 + blockIdx.x;
  const int orig = (n & 7) * 512 + (n >> 3);
  const int bm = (orig >> 2) * 128, bn = (orig & 3) * 128;
  const size_t BN = (size_t)Bb * Nn;
  f32x4 ak[4][4] = {};
  f32x4 av[4][4] = {};
  const int srow = wid*16 + (lane >> 2);
  const int scol = ((lane & 3) ^ ((lane >> 3) & 3)) * 8;    // swizzled source col
  const u16* Ap = A  + (size_t)(bm + srow) * Dd + scol;
  const u16* Kp = Bk + (size_t)(bn + srow) * Dd + scol;
  const u16* Vp = Bv + (size_t)(bn + srow) * Dd + scol;
  const int ldb = wid * 512;
  const int li = lane & 15, lk = lane >> 4;
  const int csw = (lk ^ ((li >> 1) & 3)) * 8;               // swizzled read col
#define KV_STAGE(buf, k0) do { \
    gload16(Ap + (k0), &lA[buf][ldb]); \
    gload16(Ap + (size_t)64*Dd + (k0), &lA[buf][ldb + 2048]); \
    gload16(Kp + (k0), &lK[buf][ldb]); \
    gload16(Kp + (size_t)64*Dd + (k0), &lK[buf][ldb + 2048]); \
    gload16(Vp + (k0), &lV[buf][ldb]); \
    gload16(Vp + (size_t)64*Dd + (k0), &lV[buf][ldb + 2048]); \
  } while (0)
  KV_STAGE(0, 0);
  int cur = 0;
  for (int t = 0; t < 16; ++t) {
    if (t < 15) {
      KV_STAGE(cur ^ 1, (t + 1) * 32);
      asm volatile("s_waitcnt vmcnt(6)" ::: "memory");   // stage(t) landed
    } else {
      asm volatile("s_waitcnt vmcnt(0)" ::: "memory");
    }
    __builtin_amdgcn_sched_barrier(0);
    __builtin_amdgcn_s_barrier();
    __builtin_amdgcn_sched_barrier(0);
    short8 af[4], kf[4], vf[4];
#pragma unroll
    for (int m = 0; m < 4; ++m)
      af[m] = *(const short8*)&lA[cur][(wr*64 + m*16 + li)*32 + csw];
#pragma unroll
    for (int nn2 = 0; nn2 < 4; ++nn2) {
      kf[nn2] = *(const short8*)&lK[cur][(wc*64 + nn2*16 + li)*32 + csw];
      vf[nn2] = *(const short8*)&lV[cur][(wc*64 + nn2*16 + li)*32 + csw];
    }
    __builtin_amdgcn_s_setprio(1);
#pragma unroll
    for (int m = 0; m < 4; ++m)
#pragma unroll
      for (int nn2 = 0; nn2 < 4; ++nn2) {
        ak[m][nn2] = mfma16(af[m], kf[nn2], ak[m][nn2]);
        av[m][nn2] = mfma16(af[m], vf[nn2], av[m][nn2]);
      }
    __builtin_amdgcn_s_setprio(0);
    __builtin_amdgcn_sched_barrier(0);
    __builtin_amdgcn_s_barrier();      // compute done -> next stage may overwrite
    __builtin_amdgcn_sched_barrier(0);
    cur ^= 1;
  }
#undef KV_STAGE
  const int lr = lk * 4;
#pragma unroll
  for (int m = 0; m < 4; ++m)
#pragma unroll
    for (int nn2 = 0; nn2 < 4; ++nn2) {
      int row = bm + wr*64 + m*16 + lr;
      int col = bn + wc*64 + nn2*16 + li;
      f32x4 vk = ak[m][nn2];
#pragma unroll
      for (int r = 0; r < 4; ++r)
        Ck[(size_t)(row + r) * Dd + col] = f2b(vk[r]);
      f32x4 vv = av[m][nn2];
      union { u16 o[4]; short4v v4; } ou;
#pragma unroll
      for (int r = 0; r < 4; ++r) ou.o[r] = f2b(vv[r]);
      // vT[col][row..row+3] — 8B contiguous per lane
      *(short4v*)&CvT[(size_t)col * BN + row] = ou.v4;
    }
}

// ---------------- GEMM 64x64 (small M): dbuf + counted vmcnt -----------------
// EP: 0 = bf16 out; 1 = f32 out + residual; 2 = bf16 out + bias + relu;
//     3 = f32 out + bias + residual
template<int EP>
__global__ __launch_bounds__(256) void gemm64(const u16* __restrict__ A,
    const u16* __restrict__ Bw, void* __restrict__ Cp,
    const float* __restrict__ bias, const float* __restrict__ res,
    int N, int K) {
  __shared__ u16 lA[2][64*32];
  __shared__ u16 lB[2][64*32];
  const int tid = threadIdx.x, lane = tid & 63, wid = tid >> 6;
  const int wr = wid >> 1, wc = wid & 1;
  const int bm = blockIdx.y * 64, bn = blockIdx.x * 64;
  f32x4 acc[2][2] = {};
  const int srow = wid*16 + (lane >> 2);
  const int scol = ((lane & 3) ^ ((lane >> 3) & 3)) * 8;
  const u16* Ap = A + (size_t)(bm + srow) * K + scol;
  const u16* Bp = Bw + (size_t)(bn + srow) * K + scol;
  const int ldb = wid * 512;
  const int li = lane & 15, lk = lane >> 4;
  const int csw = (lk ^ ((li >> 1) & 3)) * 8;
  const int nsteps = K >> 5;
  gload16(Ap, &lA[0][ldb]);
  gload16(Bp, &lB[0][ldb]);
  int cur = 0;
  for (int t = 0; t < nsteps; ++t) {
    if (t + 1 < nsteps) {
      const int k0 = (t + 1) * 32;
      gload16(Ap + k0, &lA[cur ^ 1][ldb]);
      gload16(Bp + k0, &lB[cur ^ 1][ldb]);
      asm volatile("s_waitcnt vmcnt(2)" ::: "memory");
    } else {
      asm volatile("s_waitcnt vmcnt(0)" ::: "memory");
    }
    __builtin_amdgcn_sched_barrier(0);
    __builtin_amdgcn_s_barrier();
    __builtin_amdgcn_sched_barrier(0);
    short8 af[2], bf[2];
#pragma unroll
    for (int m = 0; m < 2; ++m)
      af[m] = *(const short8*)&lA[cur][(wr*32 + m*16 + li)*32 + csw];
#pragma unroll
    for (int nn2 = 0; nn2 < 2; ++nn2)
      bf[nn2] = *(const short8*)&lB[cur][(wc*32 + nn2*16 + li)*32 + csw];
    __builtin_amdgcn_s_setprio(1);
#pragma unroll
    for (int m = 0; m < 2; ++m)
#pragma unroll
      for (int nn2 = 0; nn2 < 2; ++nn2)
        acc[m][nn2] = mfma16(af[m], bf[nn2], acc[m][nn2]);
    __builtin_amdgcn_s_setprio(0);
    __builtin_amdgcn_sched_barrier(0);
    __builtin_amdgcn_s_barrier();
    __builtin_amdgcn_sched_barrier(0);
    cur ^= 1;
  }
  const int lr = lk * 4;
#pragma unroll
  for (int m = 0; m < 2; ++m)
#pragma unroll
    for (int nn2 = 0; nn2 < 2; ++nn2) {
      int row = bm + wr*32 + m*16 + lr;
      int col = bn + wc*32 + nn2*16 + li;
      f32x4 v = acc[m][nn2];
#pragma unroll
      for (int r = 0; r < 4; ++r) {
        size_t off = (size_t)(row + r) * N + col;
        float x = v[r];
        if constexpr (EP == 0) ((u16*)Cp)[off] = f2b(x);
        else if constexpr (EP == 1) ((float*)Cp)[off] = x + res[off];
        else if constexpr (EP == 2) { x += bias[col]; ((u16*)Cp)[off] = f2b(x > 0.f ? x : 0.f); }
        else ((float*)Cp)[off] = x + bias[col] + res[off];
      }
    }
}

// ---------------- attention pass A: dots + column softmax + renorm prep ------
__global__ __launch_bounds__(256) void attn_a(const u16* __restrict__ q,
    const u16* __restrict__ kk, u16* __restrict__ attnb,
    float* __restrict__ rowsum, float* __restrict__ attn_mean) {
  const int jt = blockIdx.x, b = blockIdx.y;
  const int tid = threadIdx.x, lane = tid & 63, wid = tid >> 6;
  __shared__ float sc[64][129];   // [j_local][ih]
  __shared__ float red[4][64];
  const int li = lane & 15, lk = lane >> 4;
#pragma unroll
  for (int hh = 0; hh < 2; ++hh) {
    const int h = wid * 2 + hh;
    const u16* qb = q + (((size_t)b*16 + li)*8 + h)*64 + lk*8;
    short8 a0 = *(const short8*)qb;
    short8 a1 = *(const short8*)(qb + 32);
#pragma unroll
    for (int n = 0; n < 4; ++n) {
      const u16* kb = kk + ((size_t)b*Nn + jt*64 + n*16 + li)*Dd + h*64 + lk*8;
      f32x4 acc = {};
      acc = mfma16(a0, *(const short8*)kb, acc);
      acc = mfma16(a1, *(const short8*)(kb + 32), acc);
#pragma unroll
      for (int r = 0; r < 4; ++r)
        sc[n*16 + li][(lk*4 + r)*8 + h] = acc[r] * SCALE;
    }
  }
  __syncthreads();
  const int jl = tid & 63, qt = tid >> 6;
  float mx = -1e30f;
#pragma unroll
  for (int e = 0; e < 32; ++e) mx = fmaxf(mx, sc[jl][qt*32 + e]);
  red[qt][jl] = mx;
  __syncthreads();
  float M = fmaxf(fmaxf(red[0][jl], red[1][jl]), fmaxf(red[2][jl], red[3][jl]));
  __syncthreads();
  float s = 0.f;
#pragma unroll
  for (int e = 0; e < 32; ++e) {
    float ev = __expf(sc[jl][qt*32 + e] - M);
    sc[jl][qt*32 + e] = ev; s += ev;
  }
  red[qt][jl] = s;
  __syncthreads();
  float S = red[0][jl] + red[1][jl] + red[2][jl] + red[3][jl];
  float inv = 1.f / S;
#pragma unroll
  for (int e = 0; e < 32; ++e)
    sc[jl][qt*32 + e] = sc[jl][qt*32 + e] * inv + EPSR;   // attn_before + EPS
  __syncthreads();
  if (tid < 128) {
    float rs = 0.f;
    for (int j2 = 0; j2 < 64; ++j2) rs += sc[j2][tid];
    atomicAdd(&rowsum[b*128 + tid], rs);
  }
#pragma unroll
  for (int e = 0; e < 32; ++e) {
    int r = qt*32 + e;
    attnb[((size_t)b*128 + r)*Nn + jt*64 + jl] = f2b(sc[jl][r]);
  }
  if (attn_mean != nullptr && tid < 64) {
    for (int i = 0; i < 16; ++i) {
      float sm = 0.f;
#pragma unroll
      for (int h = 0; h < 8; ++h) sm += sc[tid][i*8 + h];
      attn_mean[((size_t)b*16 + i)*Nn + jt*64 + tid] = sm * 0.125f - EPSR;
    }
  }
}

// ---------------- attention pass B: partial updates = attn @ v ---------------
// vT layout: [d_out = h*64+d][b*N + j]. j split 4 ways for occupancy.
// Tpart layout: [js][b][h][i(16)][d(64)] f32.
__global__ __launch_bounds__(256) void attn_b(const u16* __restrict__ attnb,
    const u16* __restrict__ vT, float* __restrict__ Tpart) {
  const int h = blockIdx.x, js = blockIdx.y, b = blockIdx.z;
  const int lane = threadIdx.x & 63, wid = threadIdx.x >> 6;
  const int li = lane & 15, lk = lane >> 4;
  const size_t BN = (size_t)Bb * Nn;
  const int j0 = js * 1024;
  const u16* Ap = attnb + ((size_t)b*128 + li*8 + h)*Nn + j0 + lk*8;
  const u16* Bp = vT + (size_t)(h*64 + wid*16 + li)*BN + (size_t)b*Nn + j0 + lk*8;
  f32x4 acc[4] = {};
  for (int k0 = 0; k0 < 1024; k0 += 128) {
#pragma unroll
    for (int e = 0; e < 4; ++e)
      acc[e] = mfma16(*(const short8*)(Ap + k0 + e*32),
                      *(const short8*)(Bp + k0 + e*32), acc[e]);
  }
  float* Tout = Tpart + ((((size_t)js * Bb + b) * 8 + h) * 16) * 64;
#pragma unroll
  for (int r = 0; r < 4; ++r) {
    int i = lk*4 + r;
    float t = acc[0][r] + acc[1][r] + acc[2][r] + acc[3][r];
    Tout[(size_t)i * 64 + wid*16 + li] = t;
  }
}

// combine partials + renormalize: updb[(b*16+i)*512 + h*64+d]
__global__ void upd_c(const float* __restrict__ Tpart,
    const float* __restrict__ rs, u16* __restrict__ updb) {
  int idx = blockIdx.x * 256 + threadIdx.x;   // 262144 total
  int o = idx & 511, bi = idx >> 9;
  int b = bi >> 4, i = bi & 15;
  int h = o >> 6, d = o & 63;
  size_t base = (((size_t)b * 8 + h) * 16 + i) * 64 + d;
  const size_t stride = (size_t)Bb * 8 * 16 * 64;
  float t = Tpart[base] + Tpart[base + stride]
          + Tpart[base + 2*stride] + Tpart[base + 3*stride];
  updb[idx] = f2b(t / rs[b * 128 + i * 8 + h]);
}

// ---------------- small utility kernels --------------------------------------
__global__ void cvt_w(const float* __restrict__ s, u16* __restrict__ d, int n) {
  int i = blockIdx.x*256 + threadIdx.x;
  if (i < n) d[i] = f2b(s[i]);
}
// tiled transpose+convert: d[C][R] = bf16(s[R][C]^T)
__global__ __launch_bounds__(256) void tr_cvt(const float* __restrict__ s,
    u16* __restrict__ d, int R, int C) {
  __shared__ u16 t[32][33];
  const int c0 = blockIdx.x*32, r0 = blockIdx.y*32;
  const int tr = threadIdx.x >> 3, tc4 = (threadIdx.x & 7)*4;
  float4 v = *(const float4*)&s[(size_t)(r0+tr)*C + c0 + tc4];
  t[tr][tc4+0] = f2b(v.x); t[tr][tc4+1] = f2b(v.y);
  t[tr][tc4+2] = f2b(v.z); t[tr][tc4+3] = f2b(v.w);
  __syncthreads();
  const int oc = threadIdx.x >> 3, or4 = (threadIdx.x & 7)*4;
  union { u16 o[4]; short4v v4; } ou;
#pragma unroll
  for (int e = 0; e < 4; ++e) ou.o[e] = t[or4+e][oc];
  *(short4v*)&d[(size_t)(c0+oc)*R + r0 + or4] = ou.v4;
}
__global__ void copy_f32v4(const float* __restrict__ s, float* __restrict__ d, int n4) {
  int i = blockIdx.x*256 + threadIdx.x;
  if (i < n4) ((float4*)d)[i] = ((const float4*)s)[i];
}

extern "C" void kernel_launch(void* const* d_in, const int* in_sizes, int n_in,
                              void* d_out, int out_size, void* d_ws, size_t ws_size,
                              hipStream_t stream) {
  (void)in_sizes; (void)n_in; (void)out_size; (void)ws_size;
  const float* inputs  = (const float*)d_in[0];
  const float* cond    = (const float*)d_in[1];
  const float* ln_in_g = (const float*)d_in[2];
  const float* ln_in_b = (const float*)d_in[3];
  const float* Wk = (const float*)d_in[4];
  const float* Wv = (const float*)d_in[5];
  const float* Wq = (const float*)d_in[6];
  const float* Wo = (const float*)d_in[7];
  const float* ln_s_g = (const float*)d_in[8];
  const float* ln_s_b = (const float*)d_in[9];
  const float* ln_f_g = (const float*)d_in[10];
  const float* ln_f_b = (const float*)d_in[11];
  const float* W1 = (const float*)d_in[12];
  const float* b1 = (const float*)d_in[13];
  const float* W2 = (const float*)d_in[14];
  const float* b2 = (const float*)d_in[15];
  float* out_slots = (float*)d_out;
  float* out_amean = (float*)d_out + (size_t)Bb*NSs*Dd;

  char* w = (char*)d_ws;
  auto alloc = [&](size_t bytes) {
    char* p = w; w += (bytes + 255) & ~(size_t)255; return p;
  };
  u16*  xn    = (u16*)alloc((size_t)Bb*Nn*Dd*2);
  u16*  kbuf  = (u16*)alloc((size_t)Bb*Nn*Dd*2);
  u16*  vT    = (u16*)alloc((size_t)Bb*Nn*Dd*2);   // [512][B*N]
  u16*  attnb = (u16*)alloc((size_t)Bb*128*Nn*2);
  float* Tpart = (float*)alloc((size_t)4*Bb*8*16*64*4);  // [js][b][h][i][d]
  float* slots = (float*)alloc((size_t)Bb*NSs*Dd*4);
  u16*  qb    = (u16*)alloc((size_t)Bb*NSs*Dd*2);
  u16*  snb   = (u16*)alloc((size_t)Bb*NSs*Dd*2);
  u16*  s2nb  = (u16*)alloc((size_t)Bb*NSs*Dd*2);
  u16*  h1b   = (u16*)alloc((size_t)Bb*NSs*DFF*2);
  u16*  updb  = (u16*)alloc((size_t)Bb*NSs*Dd*2);
  float* rowsum = (float*)alloc((size_t)Bb*128*3*4);   // one per iteration
  u16*  wkb = (u16*)alloc(262144*2);
  u16*  wvb = (u16*)alloc(262144*2);
  u16*  wqb = (u16*)alloc(262144*2);
  u16*  wob = (u16*)alloc(262144*2);
  u16*  w1t = (u16*)alloc((size_t)1048576*2);
  u16*  w2t = (u16*)alloc((size_t)1048576*2);

  // weights -> bf16 (W1/W2 transposed so B-operand is [out,K] row-major)
  cvt_w<<<1024, 256, 0, stream>>>(Wk, wkb, 262144);
  cvt_w<<<1024, 256, 0, stream>>>(Wv, wvb, 262144);
  cvt_w<<<1024, 256, 0, stream>>>(Wq, wqb, 262144);
  cvt_w<<<1024, 256, 0, stream>>>(Wo, wob, 262144);
  tr_cvt<<<dim3(64, 16), 256, 0, stream>>>(W1, w1t, 512, 2048);
  tr_cvt<<<dim3(16, 64), 256, 0, stream>>>(W2, w2t, 2048, 512);
  // slots <- conditioning; rowsum <- 0 (all 3 iterations)
  copy_f32v4<<<256, 256, 0, stream>>>(cond, slots, 65536);
  (void)hipMemsetAsync(rowsum, 0, (size_t)Bb*128*3*4, stream);
  // x = LN(inputs) -> bf16
  ln_rows<<<Bb*Nn/4, 256, 0, stream>>>(inputs, ln_in_g, ln_in_b, xn, Bb*Nn);
  // fused: k = x @ Wk^T  [B*N,512]  and  vT = (x @ Wv^T)^T  [512, B*N]
  gemm_kv<<<dim3(4, Bb*Nn/128), 256, 0, stream>>>(xn, wkb, wvb, kbuf, vT);

  for (int it = 0; it < 3; ++it) {
    float* rsp = rowsum + (size_t)it * Bb * 128;
    ln_rows<<<128, 256, 0, stream>>>(slots, ln_s_g, ln_s_b, snb, Bb*NSs);
    gemm64<0><<<dim3(8, 8), 256, 0, stream>>>(snb, wqb, qb, nullptr, nullptr, 512, 512);
    attn_a<<<dim3(Nn/64, Bb), 256, 0, stream>>>(qb, kbuf, attnb, rsp,
                                                it == 2 ? out_amean : nullptr);
    attn_b<<<dim3(Hh, 4, Bb), 256, 0, stream>>>(attnb, vT, Tpart);
    upd_c<<<1024, 256, 0, stream>>>(Tpart, rsp, updb);
    gemm64<1><<<dim3(8, 8), 256, 0, stream>>>(updb, wob, slots, nullptr, slots, 512, 512);
    ln_rows<<<128, 256, 0, stream>>>(slots, ln_f_g, ln_f_b, s2nb, Bb*NSs);
    gemm64<2><<<dim3(32, 8), 256, 0, stream>>>(s2nb, w1t, h1b, b1, nullptr, 2048, 512);
    gemm64<3><<<dim3(8, 8), 256, 0, stream>>>(h1b, w2t, slots, b2, slots, 512, 2048);
  }
  copy_f32v4<<<256, 256, 0, stream>>>(slots, out_slots, 65536);
}